// Round 3
// baseline (196.015 us; speedup 1.0000x reference)
//
#include <hip/hip_runtime.h>

// STKBranch double-softmax attention, f16-MFMA 2-pass, R14:
//   - OCCUPANCY VIA GRID: ROWS=64, 256-thread blocks (4 waves x 16 q-rows),
//     grid = 32 heads x 32 q-tiles = 1024 blocks -> 4 blocks/CU (R12/R13 had 2).
//     Same 16 waves/CU cap as R12 but in 4 independent 4-wave barrier groups:
//     convoys shrink, blocks overlap each other's stage/lgkm stalls.
//   - keeps R12 per-wave shape (16 rows, single s1/l2) and R12/R13 pipeline:
//     swapped QK^T (C=KxQ^T) -> P feeds PV from registers as 16x16x16 B-frag;
//     no Ps/Qs LDS; Ks/Vt double-buffered; reg prefetch kt+2; 1 barrier/tile;
//     scale*2*log2e folded into Q frags.
// Math: L = scale*q@k^T ; w = softmax(2L) ; attn = softmax(L*w) ; out = attn@v
// |L| <= ~7 -> no max-subtraction. B=4 H=8 N=2048 D=64 fp32 io.

typedef _Float16 f16;
typedef f16 f16x8 __attribute__((ext_vector_type(8)));
typedef f16 f16x4 __attribute__((ext_vector_type(4)));
typedef float f32x4 __attribute__((ext_vector_type(4)));

#define MFMA32(a, b, c) __builtin_amdgcn_mfma_f32_16x16x32_f16((a), (b), (c), 0, 0, 0)
#define MFMA16(a, b, c) __builtin_amdgcn_mfma_f32_16x16x16f16((a), (b), (c), 0, 0, 0)
#define EXP2(x) __builtin_amdgcn_exp2f(x)   // v_exp_f32: D = 2^S0

#define N_CTX 2048
#define DH 64
#define KT 64
#define NKT (N_CTX / KT)
#define ROWS 64           // 4 waves x 16 q-rows
#define QS 72             // universal LDS row stride (f16): 144 B

#define C2 2.885390081777927f    // 2*log2(e), folded into Q fragments

__device__ inline unsigned pk(float a, float b) {
    typedef __fp16 fp16x2_t __attribute__((ext_vector_type(2)));
    union { fp16x2_t v; unsigned u; } x;
    x.v = __builtin_amdgcn_cvt_pkrtz(a, b);
    return x.u;
}

__global__ __launch_bounds__(256, 4)
void stk_attn_mfma(const float* __restrict__ qg, const float* __restrict__ kg,
                   const float* __restrict__ vglob, const float* __restrict__ sg,
                   float* __restrict__ og) {
    __shared__ f16 Ks[2][KT * QS];      // 18432 B (double-buffered), [key][d]
    __shared__ f16 Vt[2][DH * QS];      // 18432 B (double-buffered), [d][key]
                                        // total 36864 B -> 4 blocks/CU

    const int tid  = threadIdx.x;
    const int wv   = tid >> 6;        // 0..3
    const int lane = tid & 63;
    const int l15  = lane & 15;
    const int q4   = lane >> 4;
    const int vp   = tid & 31;        // V staging: key pair (2vp, 2vp+1)
    const int vgr  = tid >> 5;        // V staging: d-octet (0..7 -> d = vgr*8..+7)
    const int bh   = blockIdx.x & 31; // XCD swizzle: head h -> blocks h+32j -> XCD h%8
    const int q0   = (blockIdx.x >> 5) * ROWS;
    const float scale2 = sg[0] * C2;  // fold 2*log2e: acc = 2L*log2e

    const float* qb = qg + (size_t)bh * N_CTX * DH;
    const float* kb = kg + (size_t)bh * N_CTX * DH;
    const float* vb = vglob + (size_t)bh * N_CTX * DH;
    float*       ob = og + (size_t)bh * N_CTX * DH;

    // ---- Q fragments direct from global (no LDS): row q0 + wv*16 + l15 ----
    // B operand of swapped QK^T: B[k=q4*8+e][col=l15] = Q[row][k]*scale2.
    f16x8 aq[2];
    {
        const float* qrow = qb + (size_t)(q0 + wv * 16 + l15) * DH;
        #pragma unroll
        for (int kc = 0; kc < 2; ++kc) {
            float4 a0 = *(const float4*)&qrow[kc * 32 + q4 * 8];
            float4 a1 = *(const float4*)&qrow[kc * 32 + q4 * 8 + 4];
            union { f16x8 h; unsigned u[4]; } A;
            A.u[0] = pk(a0.x * scale2, a0.y * scale2);
            A.u[1] = pk(a0.z * scale2, a0.w * scale2);
            A.u[2] = pk(a1.x * scale2, a1.y * scale2);
            A.u[3] = pk(a1.z * scale2, a1.w * scale2);
            aq[kc] = A.h;
        }
    }

    // loop-invariant LDS lane bases (all ds offsets below are immediates)
    f16* const ks_w  = &Ks[0][0];                        // + staging idx
    const f16* const ks_r = &Ks[0][l15 * QS + q4 * 8];   // A-frag of QK^T: K row l15
    f16* const vt_w  = &Vt[0][(vgr * 8) * QS + 2 * vp];
    const f16* const vt_r = &Vt[0][l15 * QS + q4 * 4];   // A-frag of PV: V^T row l15
    const int KSB = KT * QS;                             // Ks/Vt buffer stride (f16)

    // =============== PASS 1: s1 = sum_k exp(2L) per q-row ===============
    float s1 = 0.f;
    float4 kr[4];
    #pragma unroll
    for (int it = 0; it < 4; ++it) {
        int idx = it * 256 + tid;
        kr[it] = *(const float4*)&kb[((size_t)(idx >> 4)) * DH + (idx & 15) * 4];
    }
    #pragma unroll
    for (int it = 0; it < 4; ++it) {
        int idx = it * 256 + tid;
        *(uint2*)&ks_w[(idx >> 4) * QS + (idx & 15) * 4] =
            make_uint2(pk(kr[it].x, kr[it].y), pk(kr[it].z, kr[it].w));
    }
    #pragma unroll
    for (int it = 0; it < 4; ++it) {
        int idx = it * 256 + tid;
        kr[it] = *(const float4*)&kb[((size_t)KT + (idx >> 4)) * DH + (idx & 15) * 4];
    }
    __syncthreads();

    for (int kt = 0; kt < NKT; ++kt) {
        const int cur = (kt & 1) * KSB, nxt = KSB - cur;
        #pragma unroll
        for (int it = 0; it < 4; ++it) {
            int idx = it * 256 + tid;
            *(uint2*)&ks_w[nxt + (idx >> 4) * QS + (idx & 15) * 4] =
                make_uint2(pk(kr[it].x, kr[it].y), pk(kr[it].z, kr[it].w));
        }
        {
            int tn = (kt + 2 < NKT) ? kt + 2 : NKT - 1;
            #pragma unroll
            for (int it = 0; it < 4; ++it) {
                int idx = it * 256 + tid;
                kr[it] = *(const float4*)&kb[((size_t)tn * KT + (idx >> 4)) * DH + (idx & 15) * 4];
            }
        }
        #pragma unroll
        for (int kgi = 0; kgi < 4; ++kgi) {
            f16x8 b0 = *(const f16x8*)&ks_r[cur + kgi * 16 * QS];
            f16x8 b1 = *(const f16x8*)&ks_r[cur + kgi * 16 * QS + 32];
            f32x4 acc = {0.f, 0.f, 0.f, 0.f};
            acc = MFMA32(b0, aq[0], acc);   // swapped: C[key][q], lane q = l15
            acc = MFMA32(b1, aq[1], acc);
            s1 += EXP2(acc[0]);
            s1 += EXP2(acc[1]);
            s1 += EXP2(acc[2]);
            s1 += EXP2(acc[3]);
        }
        __syncthreads();
    }
    // reduce across q4 groups (key partitions): lanes l15, l15+16, l15+32, l15+48
    s1 += __shfl_xor(s1, 16, 64);
    s1 += __shfl_xor(s1, 32, 64);
    const float inv1 = 0.5f / s1;    // e2 = exp2((acc*e1) * 0.5/s1)  [acc = 2L*log2e]

    // =============== PASS 2: e2, O^T += V^T P^T ===============
    float l2 = 0.f;
    f32x4 O[4];
    #pragma unroll
    for (int dt = 0; dt < 4; ++dt) O[dt] = (f32x4){0.f, 0.f, 0.f, 0.f};

    float4 vr0, vr1, vr2, vr3;  // V prefetch: keys 2vp/2vp+1, d = vgr*8..+7
    // prologue: Ks[0]<-K(0), Vt[0]<-V(0); kr<-K(1), vr<-V(1)
    #pragma unroll
    for (int it = 0; it < 4; ++it) {
        int idx = it * 256 + tid;
        kr[it] = *(const float4*)&kb[((size_t)(idx >> 4)) * DH + (idx & 15) * 4];
    }
    #pragma unroll
    for (int it = 0; it < 4; ++it) {
        int idx = it * 256 + tid;
        *(uint2*)&ks_w[(idx >> 4) * QS + (idx & 15) * 4] =
            make_uint2(pk(kr[it].x, kr[it].y), pk(kr[it].z, kr[it].w));
    }
    {
        const float* vs = vb + ((size_t)(2 * vp)) * DH + vgr * 8;
        float4 a0 = *(const float4*)(vs);
        float4 a1 = *(const float4*)(vs + 4);
        float4 b0 = *(const float4*)(vs + DH);
        float4 b1 = *(const float4*)(vs + DH + 4);
        #pragma unroll
        for (int j = 0; j < 4; ++j) {
            *(unsigned*)&vt_w[j * QS] = pk(((const float*)&a0)[j], ((const float*)&b0)[j]);
            *(unsigned*)&vt_w[(4 + j) * QS] = pk(((const float*)&a1)[j], ((const float*)&b1)[j]);
        }
        const float* vs1 = vb + ((size_t)(KT + 2 * vp)) * DH + vgr * 8;
        vr0 = *(const float4*)(vs1);
        vr1 = *(const float4*)(vs1 + 4);
        vr2 = *(const float4*)(vs1 + DH);
        vr3 = *(const float4*)(vs1 + DH + 4);
    }
    #pragma unroll
    for (int it = 0; it < 4; ++it) {
        int idx = it * 256 + tid;
        kr[it] = *(const float4*)&kb[((size_t)KT + (idx >> 4)) * DH + (idx & 15) * 4];
    }
    __syncthreads();

    for (int kt = 0; kt < NKT; ++kt) {
        const int cur = (kt & 1) * KSB, nxt = KSB - cur;
        // stage next K/V tile into the other buffers (overlaps all compute below)
        #pragma unroll
        for (int it = 0; it < 4; ++it) {
            int idx = it * 256 + tid;
            *(uint2*)&ks_w[nxt + (idx >> 4) * QS + (idx & 15) * 4] =
                make_uint2(pk(kr[it].x, kr[it].y), pk(kr[it].z, kr[it].w));
        }
        #pragma unroll
        for (int j = 0; j < 4; ++j) {
            *(unsigned*)&vt_w[nxt + j * QS] = pk(((const float*)&vr0)[j], ((const float*)&vr2)[j]);
            *(unsigned*)&vt_w[nxt + (4 + j) * QS] = pk(((const float*)&vr1)[j], ((const float*)&vr3)[j]);
        }
        // QK^T (swapped) on Ks[cur] + softmax chain; P stays in registers as
        // the ready-made B-fragment of the 16x16x16 PV MFMA.
        f16x4 pfr[4];
        #pragma unroll
        for (int kgi = 0; kgi < 4; ++kgi) {
            f16x8 b0 = *(const f16x8*)&ks_r[cur + kgi * 16 * QS];
            f16x8 b1 = *(const f16x8*)&ks_r[cur + kgi * 16 * QS + 32];
            f32x4 acc = {0.f, 0.f, 0.f, 0.f};
            acc = MFMA32(b0, aq[0], acc);
            acc = MFMA32(b1, aq[1], acc);
            float e2r[4];
            #pragma unroll
            for (int r = 0; r < 4; ++r) {
                float a  = acc[r];
                float e1 = EXP2(a);
                float e2 = EXP2((a * e1) * inv1);
                l2 += e2;
                e2r[r] = e2;
            }
            union { f16x4 h; unsigned u[2]; } P;
            P.u[0] = pk(e2r[0], e2r[1]);
            P.u[1] = pk(e2r[2], e2r[3]);
            pfr[kgi] = P.h;
        }
        // prefetch K(kt+2), V(kt+2) (clamped; loads in flight during PV)
        {
            int tn = (kt + 2 < NKT) ? kt + 2 : NKT - 1;
            #pragma unroll
            for (int it = 0; it < 4; ++it) {
                int idx = it * 256 + tid;
                kr[it] = *(const float4*)&kb[((size_t)tn * KT + (idx >> 4)) * DH + (idx & 15) * 4];
            }
            const float* vs = vb + ((size_t)tn * KT + 2 * vp) * DH + vgr * 8;
            vr0 = *(const float4*)(vs);
            vr1 = *(const float4*)(vs + 4);
            vr2 = *(const float4*)(vs + DH);
            vr3 = *(const float4*)(vs + DH + 4);
        }
        // PV: O^T[d][q] += sum_key V^T[d][key] * P^T[key][q], 16x16x16 MFMA,
        // A-fragment = 4 consecutive keys of V^T row (dt*16+l15) -> ds_read_b64.
        #pragma unroll
        for (int kgi = 0; kgi < 4; ++kgi) {
            #pragma unroll
            for (int dt = 0; dt < 4; ++dt) {
                f16x4 av = *(const f16x4*)&vt_r[cur + dt * 16 * QS + kgi * 16];
                O[dt] = MFMA16(av, pfr[kgi], O[dt]);
            }
        }
        __syncthreads();   // swap: protects Ks/Vt cur<->nxt for next iteration
    }

    // ---- finalize: lane holds O^T[d = dt*16+q4*4+r][q = wv*16+l15] ----
    l2 += __shfl_xor(l2, 16, 64);
    l2 += __shfl_xor(l2, 32, 64);
    const float invl2 = 1.0f / l2;
    const size_t orow = (size_t)(q0 + wv * 16 + l15) * DH;
    #pragma unroll
    for (int dt = 0; dt < 4; ++dt) {
        float4 o;
        o.x = O[dt][0] * invl2;
        o.y = O[dt][1] * invl2;
        o.z = O[dt][2] * invl2;
        o.w = O[dt][3] * invl2;
        *(float4*)&ob[orow + dt * 16 + q4 * 4] = o;
    }
}

extern "C" void kernel_launch(void* const* d_in, const int* in_sizes, int n_in,
                              void* d_out, int out_size, void* d_ws, size_t ws_size,
                              hipStream_t stream) {
    const float* q = (const float*)d_in[0];
    const float* k = (const float*)d_in[1];
    const float* v = (const float*)d_in[2];
    const float* s = (const float*)d_in[3];
    float* out = (float*)d_out;
    dim3 grid(32 * 32);   // bh = blockIdx&31 (XCD swizzle), q-tile = blockIdx>>5
    stk_attn_mfma<<<grid, 256, 0, stream>>>(q, k, v, s, out);
}

// Round 4
// 175.104 us; speedup vs baseline: 1.1194x; 1.1194x over previous
//
#include <hip/hip_runtime.h>

// STKBranch double-softmax attention, f16-MFMA 2-pass, R15:
//   - REVERT to R12 shape (512 blocks, 8 waves x 16 q-rows): R13 proved
//     <16 waves/CU latency-exposed, R14 proved more blocks duplicate staging.
//   - KT=128 (was 64): halves barrier count (32/block vs 64) and doubles the
//     compute window each stage/prefetch overlaps. LDS = 71680 B via dynamic
//     extern __shared__ (>64KB static limit; 2 blocks/CU: 143KB <= 160KB).
//   - l2 via ones-MFMA: Oe = MFMA16(ones, pfr, Oe) makes Oe[0] = sum_k P[k][q]
//     (MFMA reduces over k internally) -> deletes 16 f32 adds/tile/wave + the
//     final shuffles; denominator now uses the same f16 weights as numerator.
//   - keeps: swapped QK^T (C=KxQ^T) -> P feeds PV from registers as 16x16x16
//     B-frag; no Ps/Qs LDS; Ks/Vt double-buffered; reg prefetch kt+2;
//     1 barrier/tile; scale*2*log2e folded into Q frags.
// Bank notes (all floors, 2-way free): Ks stride 72 f16 = 144B = 36 words
// (== 4 mod 32); Vt key-stride 136 f16 = 272B = 68 words (== 4 mod 32).
// Math: L = scale*q@k^T ; w = softmax(2L) ; attn = softmax(L*w) ; out = attn@v
// |L| <= ~7 -> no max-subtraction. B=4 H=8 N=2048 D=64 fp32 io.

typedef _Float16 f16;
typedef f16 f16x8 __attribute__((ext_vector_type(8)));
typedef f16 f16x4 __attribute__((ext_vector_type(4)));
typedef float f32x4 __attribute__((ext_vector_type(4)));

#define MFMA32(a, b, c) __builtin_amdgcn_mfma_f32_16x16x32_f16((a), (b), (c), 0, 0, 0)
#define MFMA16(a, b, c) __builtin_amdgcn_mfma_f32_16x16x16f16((a), (b), (c), 0, 0, 0)
#define EXP2(x) __builtin_amdgcn_exp2f(x)   // v_exp_f32: D = 2^S0

#define N_CTX 2048
#define DH 64
#define KT 128
#define NKT (N_CTX / KT)   // 16
#define ROWS 128           // 8 waves x 16 q-rows
#define QS 72              // Ks row stride (f16): 144 B
#define VS 136             // Vt key stride (f16): 272 B
#define KSB (KT * QS)      // 9216 f16 per Ks buffer (18432 B)
#define VSB (DH * VS)      // 8704 f16 per Vt buffer (17408 B)
#define LDS_BYTES ((2 * KSB + 2 * VSB) * 2)   // 71680 B

#define C2 2.885390081777927f    // 2*log2(e), folded into Q fragments

__device__ inline unsigned pk(float a, float b) {
    typedef __fp16 fp16x2_t __attribute__((ext_vector_type(2)));
    union { fp16x2_t v; unsigned u; } x;
    x.v = __builtin_amdgcn_cvt_pkrtz(a, b);
    return x.u;
}

__global__ __launch_bounds__(512, 4)
void stk_attn_mfma(const float* __restrict__ qg, const float* __restrict__ kg,
                   const float* __restrict__ vglob, const float* __restrict__ sg,
                   float* __restrict__ og) {
    extern __shared__ f16 smem[];
    f16* const KsB = smem;             // [2][KSB]  [key][d]
    f16* const VtB = smem + 2 * KSB;   // [2][VSB]  [d][key]

    const int tid  = threadIdx.x;
    const int wv   = tid >> 6;        // 0..7
    const int lane = tid & 63;
    const int l15  = lane & 15;
    const int q4   = lane >> 4;
    const int bh   = blockIdx.x & 31; // XCD swizzle: head h -> blocks h+32j -> XCD h%8
    const int q0   = (blockIdx.x >> 5) * ROWS;
    const float scale2 = sg[0] * C2;  // fold 2*log2e: acc = 2L*log2e

    const float* qb = qg + (size_t)bh * N_CTX * DH;
    const float* kb = kg + (size_t)bh * N_CTX * DH;
    const float* vb = vglob + (size_t)bh * N_CTX * DH;
    float*       ob = og + (size_t)bh * N_CTX * DH;

    // ---- Q fragments direct from global (no LDS): row q0 + wv*16 + l15 ----
    // B operand of swapped QK^T: B[k=q4*8+e][col=l15] = Q[row][k]*scale2.
    f16x8 aq[2];
    {
        const float* qrow = qb + (size_t)(q0 + wv * 16 + l15) * DH;
        #pragma unroll
        for (int kc = 0; kc < 2; ++kc) {
            float4 a0 = *(const float4*)&qrow[kc * 32 + q4 * 8];
            float4 a1 = *(const float4*)&qrow[kc * 32 + q4 * 8 + 4];
            union { f16x8 h; unsigned u[4]; } A;
            A.u[0] = pk(a0.x * scale2, a0.y * scale2);
            A.u[1] = pk(a0.z * scale2, a0.w * scale2);
            A.u[2] = pk(a1.x * scale2, a1.y * scale2);
            A.u[3] = pk(a1.z * scale2, a1.w * scale2);
            aq[kc] = A.h;
        }
    }

    // loop-invariant LDS lane bases (all ds offsets below are immediates)
    f16* const ks_w  = KsB;                            // + staging idx
    const f16* const ks_r = KsB + l15 * QS + q4 * 8;   // A-frag of QK^T: K row l15
    f16* const vt_w  = VtB + (wv * 8) * VS + 2 * lane; // wave wv stages d-octet wv*8..+7
    const f16* const vt_r = VtB + l15 * VS + q4 * 4;   // A-frag of PV: V^T row l15

    // =============== PASS 1: s1 = sum_k exp(2L) per q-row ===============
    float s1 = 0.f;
    float4 kr[4];
    #pragma unroll
    for (int it = 0; it < 4; ++it) {
        int idx = it * 512 + tid;
        kr[it] = *(const float4*)&kb[((size_t)(idx >> 4)) * DH + (idx & 15) * 4];
    }
    #pragma unroll
    for (int it = 0; it < 4; ++it) {
        int idx = it * 512 + tid;
        *(uint2*)&ks_w[(idx >> 4) * QS + (idx & 15) * 4] =
            make_uint2(pk(kr[it].x, kr[it].y), pk(kr[it].z, kr[it].w));
    }
    #pragma unroll
    for (int it = 0; it < 4; ++it) {
        int idx = it * 512 + tid;
        kr[it] = *(const float4*)&kb[((size_t)KT + (idx >> 4)) * DH + (idx & 15) * 4];
    }
    __syncthreads();

    for (int kt = 0; kt < NKT; ++kt) {
        const int curK = (kt & 1) * KSB, nxtK = KSB - curK;
        #pragma unroll
        for (int it = 0; it < 4; ++it) {
            int idx = it * 512 + tid;
            *(uint2*)&ks_w[nxtK + (idx >> 4) * QS + (idx & 15) * 4] =
                make_uint2(pk(kr[it].x, kr[it].y), pk(kr[it].z, kr[it].w));
        }
        {
            int tn = (kt + 2 < NKT) ? kt + 2 : NKT - 1;
            #pragma unroll
            for (int it = 0; it < 4; ++it) {
                int idx = it * 512 + tid;
                kr[it] = *(const float4*)&kb[((size_t)tn * KT + (idx >> 4)) * DH + (idx & 15) * 4];
            }
        }
        #pragma unroll
        for (int kgi = 0; kgi < 8; ++kgi) {
            f16x8 b0 = *(const f16x8*)&ks_r[curK + kgi * 16 * QS];
            f16x8 b1 = *(const f16x8*)&ks_r[curK + kgi * 16 * QS + 32];
            f32x4 acc = {0.f, 0.f, 0.f, 0.f};
            acc = MFMA32(b0, aq[0], acc);   // swapped: C[key][q], lane q = l15
            acc = MFMA32(b1, aq[1], acc);
            s1 += EXP2(acc[0]);
            s1 += EXP2(acc[1]);
            s1 += EXP2(acc[2]);
            s1 += EXP2(acc[3]);
        }
        __syncthreads();
    }
    // reduce across q4 groups (key partitions): lanes l15, l15+16, l15+32, l15+48
    s1 += __shfl_xor(s1, 16, 64);
    s1 += __shfl_xor(s1, 32, 64);
    const float inv1 = 0.5f / s1;    // e2 = exp2((acc*e1) * 0.5/s1)  [acc = 2L*log2e]

    // =============== PASS 2: e2, O^T += V^T P^T, l2 via ones-MFMA ===============
    f32x4 O[4];
    #pragma unroll
    for (int dt = 0; dt < 4; ++dt) O[dt] = (f32x4){0.f, 0.f, 0.f, 0.f};
    f32x4 Oe = {0.f, 0.f, 0.f, 0.f};   // Oe[r] = sum_k P[k][q=l15] (all r equal)
    const f16x4 ones = {(f16)1.f, (f16)1.f, (f16)1.f, (f16)1.f};

    float4 vr0, vr1, vr2, vr3;  // V prefetch: keys 2*lane/2*lane+1, d = wv*8..+7
    // prologue: Ks[0]<-K(0), Vt[0]<-V(0); kr<-K(1), vr<-V(1)
    #pragma unroll
    for (int it = 0; it < 4; ++it) {
        int idx = it * 512 + tid;
        kr[it] = *(const float4*)&kb[((size_t)(idx >> 4)) * DH + (idx & 15) * 4];
    }
    #pragma unroll
    for (int it = 0; it < 4; ++it) {
        int idx = it * 512 + tid;
        *(uint2*)&ks_w[(idx >> 4) * QS + (idx & 15) * 4] =
            make_uint2(pk(kr[it].x, kr[it].y), pk(kr[it].z, kr[it].w));
    }
    {
        const float* vs = vb + ((size_t)(2 * lane)) * DH + wv * 8;
        float4 a0 = *(const float4*)(vs);
        float4 a1 = *(const float4*)(vs + 4);
        float4 b0 = *(const float4*)(vs + DH);
        float4 b1 = *(const float4*)(vs + DH + 4);
        #pragma unroll
        for (int j = 0; j < 4; ++j) {
            *(unsigned*)&vt_w[j * VS] = pk(((const float*)&a0)[j], ((const float*)&b0)[j]);
            *(unsigned*)&vt_w[(4 + j) * VS] = pk(((const float*)&a1)[j], ((const float*)&b1)[j]);
        }
        const float* vs1 = vb + ((size_t)(KT + 2 * lane)) * DH + wv * 8;
        vr0 = *(const float4*)(vs1);
        vr1 = *(const float4*)(vs1 + 4);
        vr2 = *(const float4*)(vs1 + DH);
        vr3 = *(const float4*)(vs1 + DH + 4);
    }
    #pragma unroll
    for (int it = 0; it < 4; ++it) {
        int idx = it * 512 + tid;
        kr[it] = *(const float4*)&kb[((size_t)KT + (idx >> 4)) * DH + (idx & 15) * 4];
    }
    __syncthreads();

    for (int kt = 0; kt < NKT; ++kt) {
        const int curK = (kt & 1) * KSB, nxtK = KSB - curK;
        const int curV = (kt & 1) * VSB, nxtV = VSB - curV;
        // stage next K/V tile into the other buffers (overlaps all compute below)
        #pragma unroll
        for (int it = 0; it < 4; ++it) {
            int idx = it * 512 + tid;
            *(uint2*)&ks_w[nxtK + (idx >> 4) * QS + (idx & 15) * 4] =
                make_uint2(pk(kr[it].x, kr[it].y), pk(kr[it].z, kr[it].w));
        }
        #pragma unroll
        for (int j = 0; j < 4; ++j) {
            *(unsigned*)&vt_w[nxtV + j * VS] = pk(((const float*)&vr0)[j], ((const float*)&vr2)[j]);
            *(unsigned*)&vt_w[nxtV + (4 + j) * VS] = pk(((const float*)&vr1)[j], ((const float*)&vr3)[j]);
        }
        // prefetch K(kt+2), V(kt+2) (clamped; loads in flight during compute)
        {
            int tn = (kt + 2 < NKT) ? kt + 2 : NKT - 1;
            #pragma unroll
            for (int it = 0; it < 4; ++it) {
                int idx = it * 512 + tid;
                kr[it] = *(const float4*)&kb[((size_t)tn * KT + (idx >> 4)) * DH + (idx & 15) * 4];
            }
            const float* vs = vb + ((size_t)(tn * KT + 2 * lane)) * DH + wv * 8;
            vr0 = *(const float4*)(vs);
            vr1 = *(const float4*)(vs + 4);
            vr2 = *(const float4*)(vs + DH);
            vr3 = *(const float4*)(vs + DH + 4);
        }
        // per-kgi: QK^T (swapped) -> softmax chain -> P packed in regs -> PV.
        // pfr is the ready-made B-frag of the 16x16x16 PV MFMA; ones-MFMA
        // accumulates l2 into Oe on the matrix pipe (frees VALU adds).
        #pragma unroll
        for (int kgi = 0; kgi < 8; ++kgi) {
            f16x8 b0 = *(const f16x8*)&ks_r[curK + kgi * 16 * QS];
            f16x8 b1 = *(const f16x8*)&ks_r[curK + kgi * 16 * QS + 32];
            f32x4 acc = {0.f, 0.f, 0.f, 0.f};
            acc = MFMA32(b0, aq[0], acc);
            acc = MFMA32(b1, aq[1], acc);
            float e2r[4];
            #pragma unroll
            for (int r = 0; r < 4; ++r) {
                float a  = acc[r];
                float e1 = EXP2(a);
                e2r[r] = EXP2((a * e1) * inv1);
            }
            union { f16x4 h; unsigned u[2]; } P;
            P.u[0] = pk(e2r[0], e2r[1]);
            P.u[1] = pk(e2r[2], e2r[3]);
            f16x4 pfr = P.h;
            Oe = MFMA16(ones, pfr, Oe);
            #pragma unroll
            for (int dt = 0; dt < 4; ++dt) {
                f16x4 av = *(const f16x4*)&vt_r[curV + dt * 16 * VS + kgi * 16];
                O[dt] = MFMA16(av, pfr, O[dt]);
            }
        }
        __syncthreads();   // swap: protects Ks/Vt cur<->nxt for next iteration
    }

    // ---- finalize: lane holds O^T[d = dt*16+q4*4+r][q = wv*16+l15]; ----
    // Oe[0] = l2(q=l15) already reduced over all keys by the MFMA k-dim.
    const float invl2 = 1.0f / Oe[0];
    const size_t orow = (size_t)(q0 + wv * 16 + l15) * DH;
    #pragma unroll
    for (int dt = 0; dt < 4; ++dt) {
        float4 o;
        o.x = O[dt][0] * invl2;
        o.y = O[dt][1] * invl2;
        o.z = O[dt][2] * invl2;
        o.w = O[dt][3] * invl2;
        *(float4*)&ob[orow + dt * 16 + q4 * 4] = o;
    }
}

extern "C" void kernel_launch(void* const* d_in, const int* in_sizes, int n_in,
                              void* d_out, int out_size, void* d_ws, size_t ws_size,
                              hipStream_t stream) {
    const float* q = (const float*)d_in[0];
    const float* k = (const float*)d_in[1];
    const float* v = (const float*)d_in[2];
    const float* s = (const float*)d_in[3];
    float* out = (float*)d_out;
    dim3 grid(32 * 16);   // bh = blockIdx&31 (XCD swizzle), q-tile = blockIdx>>5
    stk_attn_mfma<<<grid, 512, LDS_BYTES, stream>>>(q, k, v, s, out);
}

// Round 5
// 168.734 us; speedup vs baseline: 1.1617x; 1.0378x over previous
//
#include <hip/hip_runtime.h>

// STKBranch double-softmax attention, f16-MFMA 2-pass, R16:
//   - REVERT to R12 exactly (best measured: 102 us/dispatch): 512 blocks,
//     8 waves x 16 q-rows, KT=64, static LDS 36864 B, QS=72 everywhere.
//     (R13: fewer waves -> latency-exposed. R14: more blocks -> duplicated
//     staging. R15: KT=128 bundle -> 4-way V-write banks + more PV issue.)
//   - CHANGE 1, ones-MFMA l2 (numerics proven in R15's passing run):
//     Oe = MFMA16(ones, pfr, Oe) accumulates sum_k P[k][q] on the matrix
//     pipe -> deletes the serial l2-add chain + final shuffles; denominator
//     uses exactly the f16 weights the numerator uses.
//   - CHANGE 2, s_setprio(1) around compute regions (T5): 2 independent
//     blocks/CU give cross-block phase diversity; prioritize MFMA/softmax
//     waves over the other block's staging waves.
// Math: L = scale*q@k^T ; w = softmax(2L) ; attn = softmax(L*w) ; out = attn@v
// |L| <= ~7 -> no max-subtraction. B=4 H=8 N=2048 D=64 fp32 io.

typedef _Float16 f16;
typedef f16 f16x8 __attribute__((ext_vector_type(8)));
typedef f16 f16x4 __attribute__((ext_vector_type(4)));
typedef float f32x4 __attribute__((ext_vector_type(4)));

#define MFMA32(a, b, c) __builtin_amdgcn_mfma_f32_16x16x32_f16((a), (b), (c), 0, 0, 0)
#define MFMA16(a, b, c) __builtin_amdgcn_mfma_f32_16x16x16f16((a), (b), (c), 0, 0, 0)
#define EXP2(x) __builtin_amdgcn_exp2f(x)   // v_exp_f32: D = 2^S0

#define N_CTX 2048
#define DH 64
#define KT 64
#define NKT (N_CTX / KT)
#define ROWS 128          // 8 waves x 16 q-rows
#define QS 72             // universal LDS row stride (f16): 144 B

#define C2 2.885390081777927f    // 2*log2(e), folded into Q fragments

__device__ inline unsigned pk(float a, float b) {
    typedef __fp16 fp16x2_t __attribute__((ext_vector_type(2)));
    union { fp16x2_t v; unsigned u; } x;
    x.v = __builtin_amdgcn_cvt_pkrtz(a, b);
    return x.u;
}

__global__ __launch_bounds__(512, 4)
void stk_attn_mfma(const float* __restrict__ qg, const float* __restrict__ kg,
                   const float* __restrict__ vglob, const float* __restrict__ sg,
                   float* __restrict__ og) {
    __shared__ f16 Ks[2][KT * QS];      // 18432 B (double-buffered), [key][d]
    __shared__ f16 Vt[2][DH * QS];      // 18432 B (double-buffered), [d][key]
                                        // total 36864 B

    const int tid  = threadIdx.x;
    const int wv   = tid >> 6;        // 0..7
    const int lane = tid & 63;
    const int l15  = lane & 15;
    const int q4   = lane >> 4;
    const int vp   = tid & 31;        // V staging: key pair (2vp, 2vp+1)
    const int vgr  = tid >> 5;        // V staging: d-quad (0..15 -> d = vgr*4..+3)
    const int bh   = blockIdx.x & 31; // XCD swizzle: head h -> blocks h+32j -> XCD h%8
    const int q0   = (blockIdx.x >> 5) * ROWS;
    const float scale2 = sg[0] * C2;  // fold 2*log2e: acc = 2L*log2e

    const float* qb = qg + (size_t)bh * N_CTX * DH;
    const float* kb = kg + (size_t)bh * N_CTX * DH;
    const float* vb = vglob + (size_t)bh * N_CTX * DH;
    float*       ob = og + (size_t)bh * N_CTX * DH;

    // ---- Q fragments direct from global (no LDS): row q0 + wv*16 + l15 ----
    // B operand of swapped QK^T: B[k=q4*8+e][col=l15] = Q[row][k]*scale2.
    f16x8 aq[2];
    {
        const float* qrow = qb + (size_t)(q0 + wv * 16 + l15) * DH;
        #pragma unroll
        for (int kc = 0; kc < 2; ++kc) {
            float4 a0 = *(const float4*)&qrow[kc * 32 + q4 * 8];
            float4 a1 = *(const float4*)&qrow[kc * 32 + q4 * 8 + 4];
            union { f16x8 h; unsigned u[4]; } A;
            A.u[0] = pk(a0.x * scale2, a0.y * scale2);
            A.u[1] = pk(a0.z * scale2, a0.w * scale2);
            A.u[2] = pk(a1.x * scale2, a1.y * scale2);
            A.u[3] = pk(a1.z * scale2, a1.w * scale2);
            aq[kc] = A.h;
        }
    }

    // loop-invariant LDS lane bases (all ds offsets below are immediates)
    f16* const ks_w  = &Ks[0][0];                        // + staging idx
    const f16* const ks_r = &Ks[0][l15 * QS + q4 * 8];   // A-frag of QK^T: K row l15
    f16* const vt_w  = &Vt[0][(vgr * 4) * QS + 2 * vp];
    const f16* const vt_r = &Vt[0][l15 * QS + q4 * 4];   // A-frag of PV: V^T row l15
    const int KSB = KT * QS;                             // Ks/Vt buffer stride (f16)

    // =============== PASS 1: s1 = sum_k exp(2L) per q-row ===============
    float s1 = 0.f;
    float4 kr[2];
    #pragma unroll
    for (int it = 0; it < 2; ++it) {
        int idx = it * 512 + tid;
        kr[it] = *(const float4*)&kb[((size_t)(idx >> 4)) * DH + (idx & 15) * 4];
    }
    #pragma unroll
    for (int it = 0; it < 2; ++it) {
        int idx = it * 512 + tid;
        *(uint2*)&ks_w[(idx >> 4) * QS + (idx & 15) * 4] =
            make_uint2(pk(kr[it].x, kr[it].y), pk(kr[it].z, kr[it].w));
    }
    #pragma unroll
    for (int it = 0; it < 2; ++it) {
        int idx = it * 512 + tid;
        kr[it] = *(const float4*)&kb[((size_t)KT + (idx >> 4)) * DH + (idx & 15) * 4];
    }
    __syncthreads();

    for (int kt = 0; kt < NKT; ++kt) {
        const int cur = (kt & 1) * KSB, nxt = KSB - cur;
        #pragma unroll
        for (int it = 0; it < 2; ++it) {
            int idx = it * 512 + tid;
            *(uint2*)&ks_w[nxt + (idx >> 4) * QS + (idx & 15) * 4] =
                make_uint2(pk(kr[it].x, kr[it].y), pk(kr[it].z, kr[it].w));
        }
        {
            int tn = (kt + 2 < NKT) ? kt + 2 : NKT - 1;
            #pragma unroll
            for (int it = 0; it < 2; ++it) {
                int idx = it * 512 + tid;
                kr[it] = *(const float4*)&kb[((size_t)tn * KT + (idx >> 4)) * DH + (idx & 15) * 4];
            }
        }
        __builtin_amdgcn_s_setprio(1);
        #pragma unroll
        for (int kgi = 0; kgi < 4; ++kgi) {
            f16x8 b0 = *(const f16x8*)&ks_r[cur + kgi * 16 * QS];
            f16x8 b1 = *(const f16x8*)&ks_r[cur + kgi * 16 * QS + 32];
            f32x4 acc = {0.f, 0.f, 0.f, 0.f};
            acc = MFMA32(b0, aq[0], acc);   // swapped: C[key][q], lane q = l15
            acc = MFMA32(b1, aq[1], acc);
            s1 += EXP2(acc[0]);
            s1 += EXP2(acc[1]);
            s1 += EXP2(acc[2]);
            s1 += EXP2(acc[3]);
        }
        __builtin_amdgcn_s_setprio(0);
        __syncthreads();
    }
    // reduce across q4 groups (key partitions): lanes l15, l15+16, l15+32, l15+48
    s1 += __shfl_xor(s1, 16, 64);
    s1 += __shfl_xor(s1, 32, 64);
    const float inv1 = 0.5f / s1;    // e2 = exp2((acc*e1) * 0.5/s1)  [acc = 2L*log2e]

    // =============== PASS 2: e2, O^T += V^T P^T, l2 via ones-MFMA ===============
    f32x4 O[4];
    #pragma unroll
    for (int dt = 0; dt < 4; ++dt) O[dt] = (f32x4){0.f, 0.f, 0.f, 0.f};
    f32x4 Oe = {0.f, 0.f, 0.f, 0.f};   // Oe[r] = sum_k P[k][q=l15] (all r equal)
    const f16x4 ones = {(f16)1.f, (f16)1.f, (f16)1.f, (f16)1.f};

    float4 vr0, vr1, vr2, vr3;  // V prefetch: keys 2vp/2vp+1, d = vgr*8... (d-quads vgr*4)
    // prologue: Ks[0]<-K(0), Vt[0]<-V(0); kr<-K(1), vr<-V(1)
    #pragma unroll
    for (int it = 0; it < 2; ++it) {
        int idx = it * 512 + tid;
        kr[it] = *(const float4*)&kb[((size_t)(idx >> 4)) * DH + (idx & 15) * 4];
    }
    #pragma unroll
    for (int it = 0; it < 2; ++it) {
        int idx = it * 512 + tid;
        *(uint2*)&ks_w[(idx >> 4) * QS + (idx & 15) * 4] =
            make_uint2(pk(kr[it].x, kr[it].y), pk(kr[it].z, kr[it].w));
    }
    {
        const float* vs = vb + ((size_t)2 * vp) * DH + vgr * 4;
        float4 a0 = *(const float4*)(vs);
        float4 b0 = *(const float4*)(vs + DH);
        #pragma unroll
        for (int j = 0; j < 4; ++j)
            *(unsigned*)&vt_w[j * QS] = pk(((const float*)&a0)[j], ((const float*)&b0)[j]);
        const float* vs1 = vb + ((size_t)(KT + 2 * vp)) * DH + vgr * 4;
        vr0 = *(const float4*)(vs1);
        vr2 = *(const float4*)(vs1 + DH);
    }
    #pragma unroll
    for (int it = 0; it < 2; ++it) {
        int idx = it * 512 + tid;
        kr[it] = *(const float4*)&kb[((size_t)KT + (idx >> 4)) * DH + (idx & 15) * 4];
    }
    __syncthreads();

    for (int kt = 0; kt < NKT; ++kt) {
        const int cur = (kt & 1) * KSB, nxt = KSB - cur;
        // stage next K/V tile into the other buffers (overlaps all compute below)
        #pragma unroll
        for (int it = 0; it < 2; ++it) {
            int idx = it * 512 + tid;
            *(uint2*)&ks_w[nxt + (idx >> 4) * QS + (idx & 15) * 4] =
                make_uint2(pk(kr[it].x, kr[it].y), pk(kr[it].z, kr[it].w));
        }
        #pragma unroll
        for (int j = 0; j < 4; ++j)
            *(unsigned*)&vt_w[nxt + j * QS] =
                pk(((const float*)&vr0)[j], ((const float*)&vr2)[j]);
        // QK^T (swapped) on Ks[cur] + softmax chain; P stays in registers as
        // the ready-made B-fragment of the 16x16x16 PV MFMA; ones-MFMA
        // accumulates l2 into Oe on the matrix pipe.
        __builtin_amdgcn_s_setprio(1);
        f16x4 pfr[4];
        #pragma unroll
        for (int kgi = 0; kgi < 4; ++kgi) {
            f16x8 b0 = *(const f16x8*)&ks_r[cur + kgi * 16 * QS];
            f16x8 b1 = *(const f16x8*)&ks_r[cur + kgi * 16 * QS + 32];
            f32x4 acc = {0.f, 0.f, 0.f, 0.f};
            acc = MFMA32(b0, aq[0], acc);
            acc = MFMA32(b1, aq[1], acc);
            float e2r[4];
            #pragma unroll
            for (int r = 0; r < 4; ++r) {
                float a  = acc[r];
                float e1 = EXP2(a);
                e2r[r] = EXP2((a * e1) * inv1);
            }
            union { f16x4 h; unsigned u[2]; } P;
            P.u[0] = pk(e2r[0], e2r[1]);
            P.u[1] = pk(e2r[2], e2r[3]);
            pfr[kgi] = P.h;
            Oe = MFMA16(ones, pfr[kgi], Oe);
        }
        __builtin_amdgcn_s_setprio(0);
        // prefetch K(kt+2), V(kt+2) (clamped; loads in flight during PV)
        {
            int tn = (kt + 2 < NKT) ? kt + 2 : NKT - 1;
            #pragma unroll
            for (int it = 0; it < 2; ++it) {
                int idx = it * 512 + tid;
                kr[it] = *(const float4*)&kb[((size_t)tn * KT + (idx >> 4)) * DH + (idx & 15) * 4];
            }
            const float* vs = vb + ((size_t)(tn * KT + 2 * vp)) * DH + vgr * 4;
            vr0 = *(const float4*)(vs);
            vr2 = *(const float4*)(vs + DH);
        }
        // PV from register P + Vt[cur] (written last iteration)
        __builtin_amdgcn_s_setprio(1);
        #pragma unroll
        for (int kgi = 0; kgi < 4; ++kgi) {
            #pragma unroll
            for (int dt = 0; dt < 4; ++dt) {
                f16x4 av = *(const f16x4*)&vt_r[cur + dt * 16 * QS + kgi * 16];
                O[dt] = MFMA16(av, pfr[kgi], O[dt]);
            }
        }
        __builtin_amdgcn_s_setprio(0);
        __syncthreads();   // swap: protects Ks/Vt cur<->nxt for next iteration
    }

    // ---- finalize: lane holds O^T[d = dt*16+q4*4+r][q = wv*16+l15]; ----
    // Oe[0] = l2(q=l15) already reduced over all keys by the MFMA k-dim.
    const float invl2 = 1.0f / Oe[0];
    const size_t orow = (size_t)(q0 + wv * 16 + l15) * DH;
    #pragma unroll
    for (int dt = 0; dt < 4; ++dt) {
        float4 o;
        o.x = O[dt][0] * invl2;
        o.y = O[dt][1] * invl2;
        o.z = O[dt][2] * invl2;
        o.w = O[dt][3] * invl2;
        *(float4*)&ob[orow + dt * 16 + q4 * 4] = o;
    }
}

extern "C" void kernel_launch(void* const* d_in, const int* in_sizes, int n_in,
                              void* d_out, int out_size, void* d_ws, size_t ws_size,
                              hipStream_t stream) {
    const float* q = (const float*)d_in[0];
    const float* k = (const float*)d_in[1];
    const float* v = (const float*)d_in[2];
    const float* s = (const float*)d_in[3];
    float* out = (float*)d_out;
    dim3 grid(32 * 16);   // bh = blockIdx&31 (XCD swizzle), q-tile = blockIdx>>5
    stk_attn_mfma<<<grid, 512, 0, stream>>>(q, k, v, s, out);
}

// Round 7
// 166.106 us; speedup vs baseline: 1.1801x; 1.0158x over previous
//
#include <hip/hip_runtime.h>

// STKBranch double-softmax attention, f16-MFMA 2-pass, R17 (resubmit; prior
// round was an infra container failure, no dispatch ran):
//   Base = R16 (= R12 structure + ones-MFMA l2 + setprio; 512 blocks,
//   8 waves x 16 q-rows, KT=64, static LDS 36864 B). Changes, all issue-count
//   / ordering only (no structure, no layout-visible semantics):
//   - Vt PERMUTED columns: c(key) = ((key>>2)&3)*16 + (key>>4)*4 + (key&3).
//     Each lane's PV A-frags for all 4 kgi are 16 contiguous f16 ->
//     PV reads become 8x ds_read_b128 (was 16x ds_read_b64). Writes stay
//     pk-pair adjacent + conflict-free (c(2vp+1) = c(2vp)+1).
//   - prefetch global loads issued BEFORE compute (full block in flight).
//   - per-pair interleave: softmax(2p), softmax(2p+1), then PV(pair p) ->
//     PV MFMAs overlap next pair's exp2 chain, shorter pre-barrier tail.
//   - hoisted loop-invariant staging offsets; tree-reduced s1 adds.
// Math: L = scale*q@k^T ; w = softmax(2L) ; attn = softmax(L*w) ; out = attn@v
// |L| <= ~7 -> no max-subtraction. B=4 H=8 N=2048 D=64 fp32 io.

typedef _Float16 f16;
typedef f16 f16x8 __attribute__((ext_vector_type(8)));
typedef f16 f16x4 __attribute__((ext_vector_type(4)));
typedef float f32x4 __attribute__((ext_vector_type(4)));

#define MFMA32(a, b, c) __builtin_amdgcn_mfma_f32_16x16x32_f16((a), (b), (c), 0, 0, 0)
#define MFMA16(a, b, c) __builtin_amdgcn_mfma_f32_16x16x16f16((a), (b), (c), 0, 0, 0)
#define EXP2(x) __builtin_amdgcn_exp2f(x)   // v_exp_f32: D = 2^S0

#define N_CTX 2048
#define DH 64
#define KT 64
#define NKT (N_CTX / KT)
#define ROWS 128          // 8 waves x 16 q-rows
#define QS 72             // universal LDS row stride (f16): 144 B

#define C2 2.885390081777927f    // 2*log2(e), folded into Q fragments

__device__ inline unsigned pk(float a, float b) {
    typedef __fp16 fp16x2_t __attribute__((ext_vector_type(2)));
    union { fp16x2_t v; unsigned u; } x;
    x.v = __builtin_amdgcn_cvt_pkrtz(a, b);
    return x.u;
}

__global__ __launch_bounds__(512, 4)
void stk_attn_mfma(const float* __restrict__ qg, const float* __restrict__ kg,
                   const float* __restrict__ vglob, const float* __restrict__ sg,
                   float* __restrict__ og) {
    __shared__ f16 Ks[2][KT * QS];      // 18432 B (double-buffered), [key][d]
    __shared__ f16 Vt[2][DH * QS];      // 18432 B (double-buffered), [d][c(key)]
                                        // total 36864 B

    const int tid  = threadIdx.x;
    const int wv   = tid >> 6;        // 0..7
    const int lane = tid & 63;
    const int l15  = lane & 15;
    const int q4   = lane >> 4;
    const int vp   = tid & 31;        // V staging: key pair (2vp, 2vp+1)
    const int vgr  = tid >> 5;        // V staging: d-quad (0..15 -> d = vgr*4..+3)
    const int bh   = blockIdx.x & 31; // XCD swizzle: head h -> blocks h+32j -> XCD h%8
    const int q0   = (blockIdx.x >> 5) * ROWS;
    const float scale2 = sg[0] * C2;  // fold 2*log2e: acc = 2L*log2e

    const float* qb = qg + (size_t)bh * N_CTX * DH;
    const float* kb = kg + (size_t)bh * N_CTX * DH;
    const float* vb = vglob + (size_t)bh * N_CTX * DH;
    float*       ob = og + (size_t)bh * N_CTX * DH;

    // ---- Q fragments direct from global (no LDS): row q0 + wv*16 + l15 ----
    // B operand of swapped QK^T: B[k=q4*8+e][col=l15] = Q[row][k]*scale2.
    f16x8 aq[2];
    {
        const float* qrow = qb + (size_t)(q0 + wv * 16 + l15) * DH;
        #pragma unroll
        for (int kc = 0; kc < 2; ++kc) {
            float4 a0 = *(const float4*)&qrow[kc * 32 + q4 * 8];
            float4 a1 = *(const float4*)&qrow[kc * 32 + q4 * 8 + 4];
            union { f16x8 h; unsigned u[4]; } A;
            A.u[0] = pk(a0.x * scale2, a0.y * scale2);
            A.u[1] = pk(a0.z * scale2, a0.w * scale2);
            A.u[2] = pk(a1.x * scale2, a1.y * scale2);
            A.u[3] = pk(a1.z * scale2, a1.w * scale2);
            aq[kc] = A.h;
        }
    }

    // loop-invariant staging offsets (K): idx = it*512 + tid
    int kofs[2], gofs[2];
    #pragma unroll
    for (int it = 0; it < 2; ++it) {
        int idx = it * 512 + tid;
        gofs[it] = (idx >> 4) * DH + (idx & 15) * 4;   // global f32 offset within tile
        kofs[it] = (idx >> 4) * QS + (idx & 15) * 4;   // LDS f16 offset within buffer
    }
    // V staging permuted column base: keys (2vp, 2vp+1) -> columns (c2p, c2p+1)
    const int c2p = ((vp >> 1) & 3) * 16 + (vp >> 3) * 4 + (vp & 1) * 2;

    // loop-invariant LDS lane bases (all ds offsets below are immediates)
    f16* const ks_w  = &Ks[0][0];                        // + staging idx
    const f16* const ks_r = &Ks[0][l15 * QS + q4 * 8];   // A-frag of QK^T: K row l15
    f16* const vt_w  = &Vt[0][(vgr * 4) * QS + c2p];
    const f16* const vt_r = &Vt[0][l15 * QS + q4 * 16];  // PV A-frags: 16 contiguous f16
    const int KSB = KT * QS;                             // Ks/Vt buffer stride (f16)

    // =============== PASS 1: s1 = sum_k exp(2L) per q-row ===============
    float s1 = 0.f;
    float4 kr[2];
    #pragma unroll
    for (int it = 0; it < 2; ++it)
        kr[it] = *(const float4*)&kb[gofs[it]];
    #pragma unroll
    for (int it = 0; it < 2; ++it)
        *(uint2*)&ks_w[kofs[it]] =
            make_uint2(pk(kr[it].x, kr[it].y), pk(kr[it].z, kr[it].w));
    #pragma unroll
    for (int it = 0; it < 2; ++it)
        kr[it] = *(const float4*)&kb[KT * DH + gofs[it]];
    __syncthreads();

    for (int kt = 0; kt < NKT; ++kt) {
        const int cur = (kt & 1) * KSB, nxt = KSB - cur;
        #pragma unroll
        for (int it = 0; it < 2; ++it)
            *(uint2*)&ks_w[nxt + kofs[it]] =
                make_uint2(pk(kr[it].x, kr[it].y), pk(kr[it].z, kr[it].w));
        {
            int tn = (kt + 2 < NKT) ? kt + 2 : NKT - 1;
            #pragma unroll
            for (int it = 0; it < 2; ++it)
                kr[it] = *(const float4*)&kb[(size_t)tn * KT * DH + gofs[it]];
        }
        __builtin_amdgcn_s_setprio(1);
        #pragma unroll
        for (int kgi = 0; kgi < 4; ++kgi) {
            f16x8 b0 = *(const f16x8*)&ks_r[cur + kgi * 16 * QS];
            f16x8 b1 = *(const f16x8*)&ks_r[cur + kgi * 16 * QS + 32];
            f32x4 acc = {0.f, 0.f, 0.f, 0.f};
            acc = MFMA32(b0, aq[0], acc);   // swapped: C[key][q], lane q = l15
            acc = MFMA32(b1, aq[1], acc);
            s1 += (EXP2(acc[0]) + EXP2(acc[1])) + (EXP2(acc[2]) + EXP2(acc[3]));
        }
        __builtin_amdgcn_s_setprio(0);
        __syncthreads();
    }
    // reduce across q4 groups (key partitions): lanes l15, l15+16, l15+32, l15+48
    s1 += __shfl_xor(s1, 16, 64);
    s1 += __shfl_xor(s1, 32, 64);
    const float inv1 = 0.5f / s1;    // e2 = exp2((acc*e1) * 0.5/s1)  [acc = 2L*log2e]

    // =============== PASS 2: e2, O^T += V^T P^T, l2 via ones-MFMA ===============
    f32x4 O[4];
    #pragma unroll
    for (int dt = 0; dt < 4; ++dt) O[dt] = (f32x4){0.f, 0.f, 0.f, 0.f};
    f32x4 Oe = {0.f, 0.f, 0.f, 0.f};   // Oe[r] = sum_k P[k][q=l15] (all r equal)
    const f16x4 ones = {(f16)1.f, (f16)1.f, (f16)1.f, (f16)1.f};

    float4 vr0, vr2;  // V prefetch: keys (2vp, 2vp+1), d-quad vgr*4..+3
    // prologue: Ks[0]<-K(0), Vt[0]<-V(0); kr<-K(1), vr<-V(1)
    #pragma unroll
    for (int it = 0; it < 2; ++it)
        kr[it] = *(const float4*)&kb[gofs[it]];
    #pragma unroll
    for (int it = 0; it < 2; ++it)
        *(uint2*)&ks_w[kofs[it]] =
            make_uint2(pk(kr[it].x, kr[it].y), pk(kr[it].z, kr[it].w));
    {
        const float* vs = vb + ((size_t)2 * vp) * DH + vgr * 4;
        float4 a0 = *(const float4*)(vs);
        float4 b0 = *(const float4*)(vs + DH);
        #pragma unroll
        for (int j = 0; j < 4; ++j)
            *(unsigned*)&vt_w[j * QS] = pk(((const float*)&a0)[j], ((const float*)&b0)[j]);
        const float* vs1 = vb + ((size_t)(KT + 2 * vp)) * DH + vgr * 4;
        vr0 = *(const float4*)(vs1);
        vr2 = *(const float4*)(vs1 + DH);
    }
    #pragma unroll
    for (int it = 0; it < 2; ++it)
        kr[it] = *(const float4*)&kb[KT * DH + gofs[it]];
    __syncthreads();

    for (int kt = 0; kt < NKT; ++kt) {
        const int cur = (kt & 1) * KSB, nxt = KSB - cur;
        // stage next K/V tile into the other buffers (overlaps all compute below)
        #pragma unroll
        for (int it = 0; it < 2; ++it)
            *(uint2*)&ks_w[nxt + kofs[it]] =
                make_uint2(pk(kr[it].x, kr[it].y), pk(kr[it].z, kr[it].w));
        #pragma unroll
        for (int j = 0; j < 4; ++j)
            *(unsigned*)&vt_w[nxt + j * QS] =
                pk(((const float*)&vr0)[j], ((const float*)&vr2)[j]);
        // prefetch K(kt+2), V(kt+2) issued BEFORE compute (full block in flight)
        {
            int tn = (kt + 2 < NKT) ? kt + 2 : NKT - 1;
            #pragma unroll
            for (int it = 0; it < 2; ++it)
                kr[it] = *(const float4*)&kb[(size_t)tn * KT * DH + gofs[it]];
            const float* vs = vb + ((size_t)(tn * KT + 2 * vp)) * DH + vgr * 4;
            vr0 = *(const float4*)(vs);
            vr2 = *(const float4*)(vs + DH);
        }
        // per kgi-PAIR: softmax(2p), softmax(2p+1) -> PV(pair p) via b128 V-frags.
        // pfr is the ready-made B-frag of the 16x16x16 PV MFMA; ones-MFMA
        // accumulates l2 into Oe on the matrix pipe.
        __builtin_amdgcn_s_setprio(1);
        #pragma unroll
        for (int p = 0; p < 2; ++p) {
            f16x4 pfr[2];
            #pragma unroll
            for (int h = 0; h < 2; ++h) {
                const int kgi = p * 2 + h;
                f16x8 b0 = *(const f16x8*)&ks_r[cur + kgi * 16 * QS];
                f16x8 b1 = *(const f16x8*)&ks_r[cur + kgi * 16 * QS + 32];
                f32x4 acc = {0.f, 0.f, 0.f, 0.f};
                acc = MFMA32(b0, aq[0], acc);
                acc = MFMA32(b1, aq[1], acc);
                float e2r[4];
                #pragma unroll
                for (int r = 0; r < 4; ++r) {
                    float a  = acc[r];
                    float e1 = EXP2(a);
                    e2r[r] = EXP2((a * e1) * inv1);
                }
                union { f16x4 hh; unsigned u[2]; } P;
                P.u[0] = pk(e2r[0], e2r[1]);
                P.u[1] = pk(e2r[2], e2r[3]);
                pfr[h] = P.hh;
                Oe = MFMA16(ones, pfr[h], Oe);
            }
            // PV for kgi pair (2p, 2p+1): one b128 per dt covers both halves
            #pragma unroll
            for (int dt = 0; dt < 4; ++dt) {
                f16x8 av = *(const f16x8*)&vt_r[cur + dt * 16 * QS + p * 8];
                f16x4 alo = __builtin_shufflevector(av, av, 0, 1, 2, 3);
                f16x4 ahi = __builtin_shufflevector(av, av, 4, 5, 6, 7);
                O[dt] = MFMA16(alo, pfr[0], O[dt]);
                O[dt] = MFMA16(ahi, pfr[1], O[dt]);
            }
        }
        __builtin_amdgcn_s_setprio(0);
        __syncthreads();   // swap: protects Ks/Vt cur<->nxt for next iteration
    }

    // ---- finalize: lane holds O^T[d = dt*16+q4*4+r][q = wv*16+l15]; ----
    // Oe[0] = l2(q=l15) already reduced over all keys by the MFMA k-dim.
    const float invl2 = 1.0f / Oe[0];
    const size_t orow = (size_t)(q0 + wv * 16 + l15) * DH;
    #pragma unroll
    for (int dt = 0; dt < 4; ++dt) {
        float4 o;
        o.x = O[dt][0] * invl2;
        o.y = O[dt][1] * invl2;
        o.z = O[dt][2] * invl2;
        o.w = O[dt][3] * invl2;
        *(float4*)&ob[orow + dt * 16 + q4 * 4] = o;
    }
}

extern "C" void kernel_launch(void* const* d_in, const int* in_sizes, int n_in,
                              void* d_out, int out_size, void* d_ws, size_t ws_size,
                              hipStream_t stream) {
    const float* q = (const float*)d_in[0];
    const float* k = (const float*)d_in[1];
    const float* v = (const float*)d_in[2];
    const float* s = (const float*)d_in[3];
    float* out = (float*)d_out;
    dim3 grid(32 * 16);   // bh = blockIdx&31 (XCD swizzle), q-tile = blockIdx>>5
    stk_attn_mfma<<<grid, 512, 0, stream>>>(q, k, v, s, out);
}